// Round 4
// baseline (443.384 us; speedup 1.0000x reference)
//
#include <hip/hip_runtime.h>
#include <math.h>

// Problem constants (b=8, c=2048, e=64, h=8)
#define NTOK 16384
#define EDIM 64
#define HHE  512   // h*e

// ---------------------------------------------------------------------------
// Kernel 1: q/k/v = x @ W^T + b   (M=16384, N=512 per matrix, K=64)
// k-outer LDS layout (both operands transposed in LDS) so every inner-loop
// ds_read_b128 is conflict-free:
//   xt[k][tok] stride 68  -> read banks (4k + tokb) % 32, 8 distinct, bcast x8
//   wt[k][col] stride 132 -> read banks (4k + colb) % 32, 2 addr/bank = free
// Staging writes: mapping (t=tid>>2, kq2=tid&3) makes transposed scalar
// writes hit all 32 banks with 2 lanes/bank (free, m136).
// Per thread: 4 tok x 8 col; per k: 3 ds_read_b128 + 32 fma -> VALU-bound.
// ---------------------------------------------------------------------------
__global__ __launch_bounds__(256) void qkv_kernel(
    const float* __restrict__ x,
    const float* __restrict__ Wk, const float* __restrict__ bk,
    const float* __restrict__ Wq, const float* __restrict__ bq,
    const float* __restrict__ Wv, const float* __restrict__ bv,
    float* __restrict__ qb, float* __restrict__ kb, float* __restrict__ vb)
{
    __shared__ float xt[64 * 68];          // [k][tok], padded stride 68 (17.0 KB)
    __shared__ float wt[64 * 132];         // [k][col], padded stride 132 (33.8 KB)

    const int tid  = threadIdx.x;
    const int tok0 = blockIdx.x * 64;
    const int n0   = blockIdx.y * 128;
    const int z    = blockIdx.z;

    const float* W; const float* bias; float* outp;
    if      (z == 0) { W = Wk; bias = bk; outp = kb; }
    else if (z == 1) { W = Wq; bias = bq; outp = qb; }
    else             { W = Wv; bias = bv; outp = vb; }

    // ---- stage x transposed: x[tok0+t][k] -> xt[k][t]
    {
        const int t   = tid >> 2;          // 0..63
        const int kq2 = tid & 3;           // 0..3
        const float4* xg = (const float4*)(x + (size_t)(tok0 + t) * 64);
        #pragma unroll
        for (int rep = 0; rep < 4; ++rep) {
            const int kq = rep * 4 + kq2;  // 0..15
            const float4 v = xg[kq];
            xt[(kq * 4 + 0) * 68 + t] = v.x;
            xt[(kq * 4 + 1) * 68 + t] = v.y;
            xt[(kq * 4 + 2) * 68 + t] = v.z;
            xt[(kq * 4 + 3) * 68 + t] = v.w;
        }
    }
    // ---- stage W transposed: W[n0+col][k] -> wt[k][col]
    {
        const int c0  = tid >> 2;          // 0..63
        const int kq2 = tid & 3;
        #pragma unroll
        for (int rep2 = 0; rep2 < 2; ++rep2) {
            const int col = rep2 * 64 + c0;      // 0..127
            const float4* wg = (const float4*)(W + (size_t)(n0 + col) * 64);
            #pragma unroll
            for (int rep = 0; rep < 4; ++rep) {
                const int kq = rep * 4 + kq2;
                const float4 v = wg[kq];
                wt[(kq * 4 + 0) * 132 + col] = v.x;
                wt[(kq * 4 + 1) * 132 + col] = v.y;
                wt[(kq * 4 + 2) * 132 + col] = v.z;
                wt[(kq * 4 + 3) * 132 + col] = v.w;
            }
        }
    }
    __syncthreads();

    // wave-quadrant mapping: 4 waves x (32 tok x 64 col) quadrants
    const int w    = tid >> 6;             // wave id (uniform per wave)
    const int lane = tid & 63;
    const int tg   = lane >> 3;            // 0..7
    const int cg   = lane & 7;             // 0..7
    const int tokb = (w & 1) * 32 + tg * 4;     // local token base (4 tokens)
    const int colb = (w >> 1) * 64 + cg * 8;    // local col base (8 cols)

    float acc[4][8];
    #pragma unroll
    for (int t = 0; t < 4; ++t)
        #pragma unroll
        for (int c = 0; c < 8; ++c) acc[t][c] = 0.0f;

    #pragma unroll 4
    for (int k = 0; k < 64; ++k) {
        const float4 x4 = *(const float4*)&xt[k * 68 + tokb];
        const float4 wa = *(const float4*)&wt[k * 132 + colb];
        const float4 wb = *(const float4*)&wt[k * 132 + colb + 4];
        const float xr[4] = {x4.x, x4.y, x4.z, x4.w};
        const float wr[8] = {wa.x, wa.y, wa.z, wa.w, wb.x, wb.y, wb.z, wb.w};
        #pragma unroll
        for (int t = 0; t < 4; ++t)
            #pragma unroll
            for (int c = 0; c < 8; ++c)
                acc[t][c] = fmaf(xr[t], wr[c], acc[t][c]);
    }

    const float4 ba = *(const float4*)&bias[n0 + colb];
    const float4 bb = *(const float4*)&bias[n0 + colb + 4];
    #pragma unroll
    for (int t = 0; t < 4; ++t) {
        float4 oa, ob;
        oa.x = acc[t][0] + ba.x; oa.y = acc[t][1] + ba.y;
        oa.z = acc[t][2] + ba.z; oa.w = acc[t][3] + ba.w;
        ob.x = acc[t][4] + bb.x; ob.y = acc[t][5] + bb.y;
        ob.z = acc[t][6] + bb.z; ob.w = acc[t][7] + bb.w;
        float* op = outp + (size_t)(tok0 + tokb + t) * HHE + n0 + colb;
        *(float4*)op       = oa;
        *(float4*)(op + 4) = ob;
    }
}

// ---------------------------------------------------------------------------
// Kernel 2: per-token scores -> entmax_bisect -> att @ v
// R3's proven structure. Changes: med3 clamp (1 fewer VALU op/elem), 16
// bisection iters (bracketing: |tau - root| <= 0.875*2^-16 = 1.3e-5 ->
// output err ~1e-4 << 4.28e-2 threshold). NO Newton (convicted in R2).
// ---------------------------------------------------------------------------
__device__ __forceinline__ float clamp01(float z) {
    return __builtin_amdgcn_fmed3f(z, 0.0f, 1.0f);   // v_med3_f32
}
__device__ __forceinline__ float pgen(float z, float inv) {
    return z > 0.0f ? exp2f(inv * log2f(fmaxf(z, 1e-30f))) : 0.0f;
}

__global__ __launch_bounds__(256) void attn_kernel(
    float* qb,                    // read q, then write res (alias)
    const float* kb, const float* vb,
    const float* alpha_p)
{
    __shared__ float sK[4][HHE];
    __shared__ float sV[4][HHE];
    const int lane = threadIdx.x & 63;
    const int w    = threadIdx.x >> 6;
    const int tok  = blockIdx.x * 4 + w;

    const float alpha = alpha_p[0];
    const float am1   = alpha - 1.0f;

    float qr[8];
    {
        const float* qp = qb + (size_t)tok * HHE;
        const float* kp = kb + (size_t)tok * HHE;
        const float* vp = vb + (size_t)tok * HHE;
        #pragma unroll
        for (int h = 0; h < 8; ++h) {
            qr[h]                 = qp[h * 64 + lane];   // lane i holds q[h][i]
            sK[w][h * 64 + lane]  = kp[h * 64 + lane];
            sV[w][h * 64 + lane]  = vp[h * 64 + lane];
        }
    }
    __syncthreads();

    // dot row: row[j] = sum_h q[h][lane] * k[h][j]
    float row[64];
    #pragma unroll
    for (int j = 0; j < 64; ++j) row[j] = 0.0f;
    #pragma unroll
    for (int h = 0; h < 8; ++h) {
        const float qh = qr[h];
        #pragma unroll
        for (int j4 = 0; j4 < 16; ++j4) {
            const float4 k4 = *(const float4*)&sK[w][h * 64 + j4 * 4]; // broadcast
            row[j4*4+0] = fmaf(qh, k4.x, row[j4*4+0]);
            row[j4*4+1] = fmaf(qh, k4.y, row[j4*4+1]);
            row[j4*4+2] = fmaf(qh, k4.z, row[j4*4+2]);
            row[j4*4+3] = fmaf(qh, k4.w, row[j4*4+3]);
        }
    }

    // Xa = dot/sqrt(e) * (alpha-1);  1/8 and am1 fold exactly (pow-of-2)
    const float scale = am1 * 0.125f;
    #pragma unroll
    for (int j = 0; j < 64; ++j) row[j] *= scale;

    float mx = row[0];
    #pragma unroll
    for (int j = 1; j < 64; ++j) mx = fmaxf(mx, row[j]);

    float tau_lo = mx - 1.0f;                         // _gp(1, alpha) = 1
    const float tau_hi = mx - exp2f(-6.0f * am1);     // (1/64)^am1
    float dm = tau_hi - tau_lo;
    float tau_m = tau_lo;

    if (am1 == 0.5f) {
        // alpha = 1.5: p(z) = max(z,0)^2; z <= 1 always (tau >= mx-1),
        // so med3(z,0,1) == clamp == max(z,0) exactly.
        float f_lo = -1.0f;
        #pragma unroll
        for (int j = 0; j < 64; ++j) {
            float zc = clamp01(row[j] - tau_lo);
            f_lo = fmaf(zc, zc, f_lo);
        }
        for (int it = 0; it < 16; ++it) {
            dm *= 0.5f;
            tau_m = tau_lo + dm;
            float f = -1.0f;
            #pragma unroll
            for (int j = 0; j < 64; ++j) {
                float zc = clamp01(row[j] - tau_m);
                f = fmaf(zc, zc, f);
            }
            tau_lo = (f * f_lo >= 0.0f) ? tau_m : tau_lo;
        }
        float s = 0.0f;
        #pragma unroll
        for (int j = 0; j < 64; ++j) {
            float zc = clamp01(row[j] - tau_m);
            zc = zc * zc;
            row[j] = zc;
            s += zc;
        }
        const float rn = 1.0f / s;
        #pragma unroll
        for (int j = 0; j < 64; ++j) row[j] *= rn;
    } else {
        // faithful general-alpha path (unused for this problem's alpha=1.5)
        const float inv = 1.0f / am1;
        float f_lo = -1.0f;
        #pragma unroll
        for (int j = 0; j < 64; ++j) f_lo += pgen(row[j] - tau_lo, inv);
        for (int it = 0; it < 30; ++it) {
            dm *= 0.5f;
            tau_m = tau_lo + dm;
            float f = -1.0f;
            #pragma unroll
            for (int j = 0; j < 64; ++j) f += pgen(row[j] - tau_m, inv);
            tau_lo = (f * f_lo >= 0.0f) ? tau_m : tau_lo;
        }
        float s = 0.0f;
        #pragma unroll
        for (int j = 0; j < 64; ++j) {
            float pm = pgen(row[j] - tau_m, inv);
            row[j] = pm;
            s += pm;
        }
        const float rn = 1.0f / s;
        #pragma unroll
        for (int j = 0; j < 64; ++j) row[j] *= rn;
    }

    // res[h][lane] = sum_j att[lane][j] * v[h][j]
    float acc[8];
    #pragma unroll
    for (int h = 0; h < 8; ++h) acc[h] = 0.0f;
    #pragma unroll
    for (int h = 0; h < 8; ++h) {
        #pragma unroll
        for (int j4 = 0; j4 < 16; ++j4) {
            const float4 v4 = *(const float4*)&sV[w][h * 64 + j4 * 4]; // broadcast
            acc[h] = fmaf(row[j4*4+0], v4.x, acc[h]);
            acc[h] = fmaf(row[j4*4+1], v4.y, acc[h]);
            acc[h] = fmaf(row[j4*4+2], v4.z, acc[h]);
            acc[h] = fmaf(row[j4*4+3], v4.w, acc[h]);
        }
    }
    float* rp = qb + (size_t)tok * HHE;   // res overwrites q (safe: own wave only)
    #pragma unroll
    for (int h = 0; h < 8; ++h) rp[h * 64 + lane] = acc[h];
}

// ---------------------------------------------------------------------------
// Kernel 3: out = res @ Wu^T + bu   (M=16384, N=64, K=512)
// No LDS, no barriers. 1024 blocks x 256 threads; thread = 1 tok x 4 cols.
// res loads: 16 lanes/address -> HW broadcast-merge; Wu streams k-sequential
// (64B line serves 4 iterations, L1-friendly); Wu total 128 KB = L2-hot.
// ---------------------------------------------------------------------------
__global__ __launch_bounds__(256) void out_kernel(
    const float* __restrict__ resb, const float* __restrict__ Wu,
    const float* __restrict__ bu, float* __restrict__ out)
{
    const int tid  = threadIdx.x;
    const int tok  = blockIdx.x * 16 + (tid >> 4);
    const int colq = tid & 15;                      // cols colq*4 .. colq*4+3

    const float4* rp = (const float4*)(resb + (size_t)tok * HHE);
    const float4* w0 = (const float4*)(Wu + (size_t)(colq * 4 + 0) * HHE);
    const float4* w1 = (const float4*)(Wu + (size_t)(colq * 4 + 1) * HHE);
    const float4* w2 = (const float4*)(Wu + (size_t)(colq * 4 + 2) * HHE);
    const float4* w3 = (const float4*)(Wu + (size_t)(colq * 4 + 3) * HHE);

    float a0 = 0.0f, a1 = 0.0f, a2 = 0.0f, a3 = 0.0f;
    #pragma unroll 4
    for (int k4 = 0; k4 < 128; ++k4) {
        const float4 r  = rp[k4];
        const float4 q0 = w0[k4];
        const float4 q1 = w1[k4];
        const float4 q2 = w2[k4];
        const float4 q3 = w3[k4];
        a0 = fmaf(r.x, q0.x, a0); a0 = fmaf(r.y, q0.y, a0);
        a0 = fmaf(r.z, q0.z, a0); a0 = fmaf(r.w, q0.w, a0);
        a1 = fmaf(r.x, q1.x, a1); a1 = fmaf(r.y, q1.y, a1);
        a1 = fmaf(r.z, q1.z, a1); a1 = fmaf(r.w, q1.w, a1);
        a2 = fmaf(r.x, q2.x, a2); a2 = fmaf(r.y, q2.y, a2);
        a2 = fmaf(r.z, q2.z, a2); a2 = fmaf(r.w, q2.w, a2);
        a3 = fmaf(r.x, q3.x, a3); a3 = fmaf(r.y, q3.y, a3);
        a3 = fmaf(r.z, q3.z, a3); a3 = fmaf(r.w, q3.w, a3);
    }

    const float4 b4 = ((const float4*)bu)[colq];
    float4 o;
    o.x = a0 + b4.x; o.y = a1 + b4.y; o.z = a2 + b4.z; o.w = a3 + b4.w;
    *(float4*)&out[(size_t)tok * 64 + colq * 4] = o;
}

// ---------------------------------------------------------------------------
extern "C" void kernel_launch(void* const* d_in, const int* in_sizes, int n_in,
                              void* d_out, int out_size, void* d_ws, size_t ws_size,
                              hipStream_t stream)
{
    const float* x     = (const float*)d_in[0];
    const float* alpha = (const float*)d_in[1];
    const float* Wk    = (const float*)d_in[2];
    const float* bk    = (const float*)d_in[3];
    const float* Wq    = (const float*)d_in[4];
    const float* bq    = (const float*)d_in[5];
    const float* Wv    = (const float*)d_in[6];
    const float* bv    = (const float*)d_in[7];
    const float* Wu    = (const float*)d_in[8];
    const float* bu    = (const float*)d_in[9];
    float* out = (float*)d_out;

    float* ws = (float*)d_ws;
    float* qb = ws;                                  // res aliases q
    float* kb = ws + (size_t)NTOK * HHE;
    float* vb = ws + 2 * (size_t)NTOK * HHE;         // total 96 MB

    qkv_kernel<<<dim3(NTOK / 64, 4, 3), 256, 0, stream>>>(
        x, Wk, bk, Wq, bq, Wv, bv, qb, kb, vb);
    attn_kernel<<<NTOK / 4, 256, 0, stream>>>(qb, kb, vb, alpha);
    out_kernel<<<NTOK / 16, 256, 0, stream>>>(qb, Wu, bu, out);
}

// Round 5
// 233.769 us; speedup vs baseline: 1.8967x; 1.8967x over previous
//
#include <hip/hip_runtime.h>
#include <math.h>

// Problem constants (b=8, c=2048, e=64, h=8)
#define NTOK 16384
#define EDIM 64
#define HHE  512   // h*e

// ---------------------------------------------------------------------------
// Kernel 1: q/k/v = x @ W^T + b   (M=16384, N=512 per matrix, K=64)
// R4 version, unchanged (k-outer LDS, conflict-free). Held constant.
// ---------------------------------------------------------------------------
__global__ __launch_bounds__(256) void qkv_kernel(
    const float* __restrict__ x,
    const float* __restrict__ Wk, const float* __restrict__ bk,
    const float* __restrict__ Wq, const float* __restrict__ bq,
    const float* __restrict__ Wv, const float* __restrict__ bv,
    float* __restrict__ qb, float* __restrict__ kb, float* __restrict__ vb)
{
    __shared__ float xt[64 * 68];          // [k][tok], padded stride 68 (17.0 KB)
    __shared__ float wt[64 * 132];         // [k][col], padded stride 132 (33.8 KB)

    const int tid  = threadIdx.x;
    const int tok0 = blockIdx.x * 64;
    const int n0   = blockIdx.y * 128;
    const int z    = blockIdx.z;

    const float* W; const float* bias; float* outp;
    if      (z == 0) { W = Wk; bias = bk; outp = kb; }
    else if (z == 1) { W = Wq; bias = bq; outp = qb; }
    else             { W = Wv; bias = bv; outp = vb; }

    // ---- stage x transposed: x[tok0+t][k] -> xt[k][t]
    {
        const int t   = tid >> 2;          // 0..63
        const int kq2 = tid & 3;           // 0..3
        const float4* xg = (const float4*)(x + (size_t)(tok0 + t) * 64);
        #pragma unroll
        for (int rep = 0; rep < 4; ++rep) {
            const int kq = rep * 4 + kq2;  // 0..15
            const float4 v = xg[kq];
            xt[(kq * 4 + 0) * 68 + t] = v.x;
            xt[(kq * 4 + 1) * 68 + t] = v.y;
            xt[(kq * 4 + 2) * 68 + t] = v.z;
            xt[(kq * 4 + 3) * 68 + t] = v.w;
        }
    }
    // ---- stage W transposed: W[n0+col][k] -> wt[k][col]
    {
        const int c0  = tid >> 2;          // 0..63
        const int kq2 = tid & 3;
        #pragma unroll
        for (int rep2 = 0; rep2 < 2; ++rep2) {
            const int col = rep2 * 64 + c0;      // 0..127
            const float4* wg = (const float4*)(W + (size_t)(n0 + col) * 64);
            #pragma unroll
            for (int rep = 0; rep < 4; ++rep) {
                const int kq = rep * 4 + kq2;
                const float4 v = wg[kq];
                wt[(kq * 4 + 0) * 132 + col] = v.x;
                wt[(kq * 4 + 1) * 132 + col] = v.y;
                wt[(kq * 4 + 2) * 132 + col] = v.z;
                wt[(kq * 4 + 3) * 132 + col] = v.w;
            }
        }
    }
    __syncthreads();

    // wave-quadrant mapping: 4 waves x (32 tok x 64 col) quadrants
    const int w    = tid >> 6;             // wave id (uniform per wave)
    const int lane = tid & 63;
    const int tg   = lane >> 3;            // 0..7
    const int cg   = lane & 7;             // 0..7
    const int tokb = (w & 1) * 32 + tg * 4;     // local token base (4 tokens)
    const int colb = (w >> 1) * 64 + cg * 8;    // local col base (8 cols)

    float acc[4][8];
    #pragma unroll
    for (int t = 0; t < 4; ++t)
        #pragma unroll
        for (int c = 0; c < 8; ++c) acc[t][c] = 0.0f;

    #pragma unroll 4
    for (int k = 0; k < 64; ++k) {
        const float4 x4 = *(const float4*)&xt[k * 68 + tokb];
        const float4 wa = *(const float4*)&wt[k * 132 + colb];
        const float4 wb = *(const float4*)&wt[k * 132 + colb + 4];
        const float xr[4] = {x4.x, x4.y, x4.z, x4.w};
        const float wr[8] = {wa.x, wa.y, wa.z, wa.w, wb.x, wb.y, wb.z, wb.w};
        #pragma unroll
        for (int t = 0; t < 4; ++t)
            #pragma unroll
            for (int c = 0; c < 8; ++c)
                acc[t][c] = fmaf(xr[t], wr[c], acc[t][c]);
    }

    const float4 ba = *(const float4*)&bias[n0 + colb];
    const float4 bb = *(const float4*)&bias[n0 + colb + 4];
    #pragma unroll
    for (int t = 0; t < 4; ++t) {
        float4 oa, ob;
        oa.x = acc[t][0] + ba.x; oa.y = acc[t][1] + ba.y;
        oa.z = acc[t][2] + ba.z; oa.w = acc[t][3] + ba.w;
        ob.x = acc[t][4] + bb.x; ob.y = acc[t][5] + bb.y;
        ob.z = acc[t][6] + bb.z; ob.w = acc[t][7] + bb.w;
        float* op = outp + (size_t)(tok0 + tokb + t) * HHE + n0 + colb;
        *(float4*)op       = oa;
        *(float4*)(op + 4) = ob;
    }
}

// ---------------------------------------------------------------------------
// Kernel 2: per-token scores -> entmax_bisect -> att @ v
// R4 version, unchanged (med3 clamp, 16 bisection iters). Held constant.
// ---------------------------------------------------------------------------
__device__ __forceinline__ float clamp01(float z) {
    return __builtin_amdgcn_fmed3f(z, 0.0f, 1.0f);   // v_med3_f32
}
__device__ __forceinline__ float pgen(float z, float inv) {
    return z > 0.0f ? exp2f(inv * log2f(fmaxf(z, 1e-30f))) : 0.0f;
}

__global__ __launch_bounds__(256) void attn_kernel(
    float* qb,                    // read q, then write res (alias)
    const float* kb, const float* vb,
    const float* alpha_p)
{
    __shared__ float sK[4][HHE];
    __shared__ float sV[4][HHE];
    const int lane = threadIdx.x & 63;
    const int w    = threadIdx.x >> 6;
    const int tok  = blockIdx.x * 4 + w;

    const float alpha = alpha_p[0];
    const float am1   = alpha - 1.0f;

    float qr[8];
    {
        const float* qp = qb + (size_t)tok * HHE;
        const float* kp = kb + (size_t)tok * HHE;
        const float* vp = vb + (size_t)tok * HHE;
        #pragma unroll
        for (int h = 0; h < 8; ++h) {
            qr[h]                 = qp[h * 64 + lane];   // lane i holds q[h][i]
            sK[w][h * 64 + lane]  = kp[h * 64 + lane];
            sV[w][h * 64 + lane]  = vp[h * 64 + lane];
        }
    }
    __syncthreads();

    // dot row: row[j] = sum_h q[h][lane] * k[h][j]
    float row[64];
    #pragma unroll
    for (int j = 0; j < 64; ++j) row[j] = 0.0f;
    #pragma unroll
    for (int h = 0; h < 8; ++h) {
        const float qh = qr[h];
        #pragma unroll
        for (int j4 = 0; j4 < 16; ++j4) {
            const float4 k4 = *(const float4*)&sK[w][h * 64 + j4 * 4]; // broadcast
            row[j4*4+0] = fmaf(qh, k4.x, row[j4*4+0]);
            row[j4*4+1] = fmaf(qh, k4.y, row[j4*4+1]);
            row[j4*4+2] = fmaf(qh, k4.z, row[j4*4+2]);
            row[j4*4+3] = fmaf(qh, k4.w, row[j4*4+3]);
        }
    }

    // Xa = dot/sqrt(e) * (alpha-1);  1/8 and am1 fold exactly (pow-of-2)
    const float scale = am1 * 0.125f;
    #pragma unroll
    for (int j = 0; j < 64; ++j) row[j] *= scale;

    float mx = row[0];
    #pragma unroll
    for (int j = 1; j < 64; ++j) mx = fmaxf(mx, row[j]);

    float tau_lo = mx - 1.0f;                         // _gp(1, alpha) = 1
    const float tau_hi = mx - exp2f(-6.0f * am1);     // (1/64)^am1
    float dm = tau_hi - tau_lo;
    float tau_m = tau_lo;

    if (am1 == 0.5f) {
        // alpha = 1.5: p(z) = max(z,0)^2; z <= 1 always (tau >= mx-1),
        // so med3(z,0,1) == clamp == max(z,0) exactly.
        float f_lo = -1.0f;
        #pragma unroll
        for (int j = 0; j < 64; ++j) {
            float zc = clamp01(row[j] - tau_lo);
            f_lo = fmaf(zc, zc, f_lo);
        }
        for (int it = 0; it < 16; ++it) {
            dm *= 0.5f;
            tau_m = tau_lo + dm;
            float f = -1.0f;
            #pragma unroll
            for (int j = 0; j < 64; ++j) {
                float zc = clamp01(row[j] - tau_m);
                f = fmaf(zc, zc, f);
            }
            tau_lo = (f * f_lo >= 0.0f) ? tau_m : tau_lo;
        }
        float s = 0.0f;
        #pragma unroll
        for (int j = 0; j < 64; ++j) {
            float zc = clamp01(row[j] - tau_m);
            zc = zc * zc;
            row[j] = zc;
            s += zc;
        }
        const float rn = 1.0f / s;
        #pragma unroll
        for (int j = 0; j < 64; ++j) row[j] *= rn;
    } else {
        // faithful general-alpha path (unused for this problem's alpha=1.5)
        const float inv = 1.0f / am1;
        float f_lo = -1.0f;
        #pragma unroll
        for (int j = 0; j < 64; ++j) f_lo += pgen(row[j] - tau_lo, inv);
        for (int it = 0; it < 30; ++it) {
            dm *= 0.5f;
            tau_m = tau_lo + dm;
            float f = -1.0f;
            #pragma unroll
            for (int j = 0; j < 64; ++j) f += pgen(row[j] - tau_m, inv);
            tau_lo = (f * f_lo >= 0.0f) ? tau_m : tau_lo;
        }
        float s = 0.0f;
        #pragma unroll
        for (int j = 0; j < 64; ++j) {
            float pm = pgen(row[j] - tau_m, inv);
            row[j] = pm;
            s += pm;
        }
        const float rn = 1.0f / s;
        #pragma unroll
        for (int j = 0; j < 64; ++j) row[j] *= rn;
    }

    // res[h][lane] = sum_j att[lane][j] * v[h][j]
    float acc[8];
    #pragma unroll
    for (int h = 0; h < 8; ++h) acc[h] = 0.0f;
    #pragma unroll
    for (int h = 0; h < 8; ++h) {
        #pragma unroll
        for (int j4 = 0; j4 < 16; ++j4) {
            const float4 v4 = *(const float4*)&sV[w][h * 64 + j4 * 4]; // broadcast
            acc[h] = fmaf(row[j4*4+0], v4.x, acc[h]);
            acc[h] = fmaf(row[j4*4+1], v4.y, acc[h]);
            acc[h] = fmaf(row[j4*4+2], v4.z, acc[h]);
            acc[h] = fmaf(row[j4*4+3], v4.w, acc[h]);
        }
    }
    float* rp = qb + (size_t)tok * HHE;   // res overwrites q (safe: own wave only)
    #pragma unroll
    for (int h = 0; h < 8; ++h) rp[h * 64 + lane] = acc[h];
}

// ---------------------------------------------------------------------------
// Kernel 3: out = res @ Wu^T + bu   (M=16384, N=64, K=512)  — REBUILT
// k-outer LDS GEMM, same structure as qkv. Tile 64 tok x 64 m, K in 8
// chunks of 64. Bank analysis:
//   staging writes: bank (16*kq2 + t + 4c) mod 32 -> 2 lanes/bank = free
//   compute reads:  b128 at banks 4*(kk+tokq) mod 32 -> 2-way = free
// Per thread 4 tok x 4 m: per kk 2 ds_read_b128 + 16 fma. No global gather
// (R4's 16-transaction Wu loads are gone — everything streams coalesced).
// ---------------------------------------------------------------------------
__global__ __launch_bounds__(256) void out_kernel(
    const float* __restrict__ resb, const float* __restrict__ Wu,
    const float* __restrict__ bu, float* __restrict__ out)
{
    __shared__ float rT[64 * 68];        // [kk][tok]  17.4 KB
    __shared__ float wT[64 * 68];        // [kk][m]    17.4 KB

    const int tid  = threadIdx.x;
    const int tok0 = blockIdx.x * 64;

    const int t    = tid >> 2;           // 0..63 (staging: token row / Wu row)
    const int kq2  = tid & 3;            // 0..3
    const int tokq = tid >> 4;           // 0..15 (compute: 4-token group)
    const int mq   = tid & 15;           // 0..15 (compute: 4-col group)

    float acc[4][4];
    #pragma unroll
    for (int a = 0; a < 4; ++a)
        #pragma unroll
        for (int b = 0; b < 4; ++b) acc[a][b] = 0.0f;

    const float4* rg = (const float4*)(resb + (size_t)(tok0 + t) * HHE);
    const float4* wg = (const float4*)(Wu   + (size_t)t * HHE);

    for (int kc = 0; kc < 8; ++kc) {
        // ---- stage res & Wu chunks transposed into LDS
        #pragma unroll
        for (int rep = 0; rep < 4; ++rep) {
            const int kq = rep * 4 + kq2;            // 0..15 within chunk
            const float4 rv = rg[kc * 16 + kq];
            rT[(kq * 4 + 0) * 68 + t] = rv.x;
            rT[(kq * 4 + 1) * 68 + t] = rv.y;
            rT[(kq * 4 + 2) * 68 + t] = rv.z;
            rT[(kq * 4 + 3) * 68 + t] = rv.w;
            const float4 wv = wg[kc * 16 + kq];
            wT[(kq * 4 + 0) * 68 + t] = wv.x;
            wT[(kq * 4 + 1) * 68 + t] = wv.y;
            wT[(kq * 4 + 2) * 68 + t] = wv.z;
            wT[(kq * 4 + 3) * 68 + t] = wv.w;
        }
        __syncthreads();

        // ---- compute: per kk, 2 x ds_read_b128 + 16 fma
        #pragma unroll 4
        for (int kk = 0; kk < 64; ++kk) {
            const float4 a4 = *(const float4*)&rT[kk * 68 + tokq * 4];
            const float4 b4 = *(const float4*)&wT[kk * 68 + mq * 4];
            const float ar[4] = {a4.x, a4.y, a4.z, a4.w};
            const float br[4] = {b4.x, b4.y, b4.z, b4.w};
            #pragma unroll
            for (int a = 0; a < 4; ++a)
                #pragma unroll
                for (int b = 0; b < 4; ++b)
                    acc[a][b] = fmaf(ar[a], br[b], acc[a][b]);
        }
        __syncthreads();                 // LDS reused next chunk
    }

    const float4 b4 = ((const float4*)bu)[mq];
    #pragma unroll
    for (int a = 0; a < 4; ++a) {
        float4 o;
        o.x = acc[a][0] + b4.x;
        o.y = acc[a][1] + b4.y;
        o.z = acc[a][2] + b4.z;
        o.w = acc[a][3] + b4.w;
        *(float4*)&out[(size_t)(tok0 + tokq * 4 + a) * 64 + mq * 4] = o;
    }
}

// ---------------------------------------------------------------------------
extern "C" void kernel_launch(void* const* d_in, const int* in_sizes, int n_in,
                              void* d_out, int out_size, void* d_ws, size_t ws_size,
                              hipStream_t stream)
{
    const float* x     = (const float*)d_in[0];
    const float* alpha = (const float*)d_in[1];
    const float* Wk    = (const float*)d_in[2];
    const float* bk    = (const float*)d_in[3];
    const float* Wq    = (const float*)d_in[4];
    const float* bq    = (const float*)d_in[5];
    const float* Wv    = (const float*)d_in[6];
    const float* bv    = (const float*)d_in[7];
    const float* Wu    = (const float*)d_in[8];
    const float* bu    = (const float*)d_in[9];
    float* out = (float*)d_out;

    float* ws = (float*)d_ws;
    float* qb = ws;                                  // res aliases q
    float* kb = ws + (size_t)NTOK * HHE;
    float* vb = ws + 2 * (size_t)NTOK * HHE;         // total 96 MB

    qkv_kernel<<<dim3(NTOK / 64, 4, 3), 256, 0, stream>>>(
        x, Wk, bk, Wq, bq, Wv, bv, qb, kb, vb);
    attn_kernel<<<NTOK / 4, 256, 0, stream>>>(qb, kb, vb, alpha);
    out_kernel<<<NTOK / 64, 256, 0, stream>>>(qb, Wu, bu, out);
}